// Round 2
// baseline (223.701 us; speedup 1.0000x reference)
//
#include <hip/hip_runtime.h>

// Elementwise clamp: out = min(max(x, lo), hi)
// x: 33,554,432 fp32, clamp_params: [lo, hi] fp32.
// Pure streaming kernel: 256 MiB traffic -> ~43 us roofline at 6.3 TB/s.
// Round 1 -> 2: nontemporal load/store (no reuse, skip cache pollution),
// 2x float4 per thread (32 B/lane MLP), split-stream indexing for 1 KiB
// fully-coalesced wave accesses.

typedef float vf4 __attribute__((ext_vector_type(4)));

__global__ void __launch_bounds__(256) clamp_kernel(
    const vf4* __restrict__ x,
    const float* __restrict__ cp,
    vf4* __restrict__ out,
    int n4)           // number of float4s (8,388,608)
{
    const float lo = cp[0];
    const float hi = cp[1];

    const int half = n4 >> 1;                       // 4,194,304
    int i = blockIdx.x * blockDim.x + threadIdx.x;  // [0, half)
    if (i >= half) return;

    // Two independent streams: [0, half) and [half, n4) — both coalesced.
    vf4 a = __builtin_nontemporal_load(&x[i]);
    vf4 b = __builtin_nontemporal_load(&x[i + half]);

    a.x = fminf(fmaxf(a.x, lo), hi);
    a.y = fminf(fmaxf(a.y, lo), hi);
    a.z = fminf(fmaxf(a.z, lo), hi);
    a.w = fminf(fmaxf(a.w, lo), hi);

    b.x = fminf(fmaxf(b.x, lo), hi);
    b.y = fminf(fmaxf(b.y, lo), hi);
    b.z = fminf(fmaxf(b.z, lo), hi);
    b.w = fminf(fmaxf(b.w, lo), hi);

    __builtin_nontemporal_store(a, &out[i]);
    __builtin_nontemporal_store(b, &out[i + half]);
}

extern "C" void kernel_launch(void* const* d_in, const int* in_sizes, int n_in,
                              void* d_out, int out_size, void* d_ws, size_t ws_size,
                              hipStream_t stream)
{
    const vf4*  x  = (const vf4*)d_in[0];
    const float* cp = (const float*)d_in[1];
    vf4* out = (vf4*)d_out;

    const int n  = in_sizes[0];   // 33,554,432 fp32 elements
    const int n4 = n / 4;         // 8,388,608 float4s (exact)
    const int half = n4 / 2;      // 4,194,304 threads

    const int block = 256;
    const int grid = (half + block - 1) / block;   // 16,384 blocks

    clamp_kernel<<<grid, block, 0, stream>>>(x, cp, out, n4);
}